// Round 1
// 1298.897 us; speedup vs baseline: 1.3018x; 1.3018x over previous
//
#include <hip/hip_runtime.h>
#include <math.h>

#define N_NODES 50000
#define E_EDGES 800000
#define D_DIM 128
#define H_HEADS 2
#define DH_DIM 64
#define C_DIM 256

typedef unsigned short u16;
typedef unsigned int u32;
typedef __attribute__((ext_vector_type(8))) short short8v;  // 8 bf16 (4 VGPRs)
typedef __attribute__((ext_vector_type(4))) float f32x4;

// bf16 round-to-nearest-even split helpers (Dekker: x = hi + lo exactly to ~2^-17)
static __device__ __forceinline__ u16 f2bf(float x) {
    union { float f; u32 u; } a; a.f = x;
    u32 r = a.u + 0x7fffu + ((a.u >> 16) & 1u);
    return (u16)(r >> 16);
}
static __device__ __forceinline__ float bf2f(u16 h) {
    union { u32 u; float f; } a; a.u = ((u32)h) << 16;
    return a.f;
}

// ---------------------------------------------------------------------------
// K1: out = x @ W + b for W in {Wq, Wk, Wv, Wskip} (blockIdx.z selects).
// Unchanged fp32 tiled GEMM (candidate for MFMA in a later round).
// ---------------------------------------------------------------------------
__global__ __launch_bounds__(256) void qkvs_gemm(
    const float* __restrict__ x,
    const float* __restrict__ Wq, const float* __restrict__ bq,
    const float* __restrict__ Wk, const float* __restrict__ bk,
    const float* __restrict__ Wv, const float* __restrict__ bv,
    const float* __restrict__ Wsk, const float* __restrict__ bsk,
    float* __restrict__ qo, float* __restrict__ ko, float* __restrict__ vo,
    float* __restrict__ so)
{
    const float* W; const float* bias; float* out;
    switch (blockIdx.z) {
        case 0: W = Wq;  bias = bq;  out = qo; break;
        case 1: W = Wk;  bias = bk;  out = ko; break;
        case 2: W = Wv;  bias = bv;  out = vo; break;
        default: W = Wsk; bias = bsk; out = so; break;
    }
    __shared__ float As[16][65];
    __shared__ float Bs[16][64];

    const int tid = threadIdx.x;
    const int tx = tid & 15;
    const int ty = tid >> 4;
    const int m0 = blockIdx.x * 64;
    const int n0 = blockIdx.y * 64;

    const int aRow = tid >> 2;
    const int aCol = (tid & 3) * 4;
    const int bRow = tid >> 4;
    const int bCol = (tid & 15) * 4;

    float acc[4][4] = {};

    for (int k0 = 0; k0 < 128; k0 += 16) {
        int gm = m0 + aRow;
        float4 av = make_float4(0.f, 0.f, 0.f, 0.f);
        if (gm < N_NODES)
            av = *reinterpret_cast<const float4*>(&x[(size_t)gm * 128 + k0 + aCol]);
        As[aCol + 0][aRow] = av.x;
        As[aCol + 1][aRow] = av.y;
        As[aCol + 2][aRow] = av.z;
        As[aCol + 3][aRow] = av.w;

        *reinterpret_cast<float4*>(&Bs[bRow][bCol]) =
            *reinterpret_cast<const float4*>(&W[(size_t)(k0 + bRow) * 128 + n0 + bCol]);
        __syncthreads();

        #pragma unroll
        for (int kk = 0; kk < 16; ++kk) {
            float rm[4];
            #pragma unroll
            for (int i = 0; i < 4; ++i) rm[i] = As[kk][ty * 4 + i];
            float4 rn = *reinterpret_cast<float4*>(&Bs[kk][tx * 4]);
            #pragma unroll
            for (int i = 0; i < 4; ++i) {
                acc[i][0] += rm[i] * rn.x;
                acc[i][1] += rm[i] * rn.y;
                acc[i][2] += rm[i] * rn.z;
                acc[i][3] += rm[i] * rn.w;
            }
        }
        __syncthreads();
    }

    #pragma unroll
    for (int i = 0; i < 4; ++i) {
        int gm = m0 + ty * 4 + i;
        if (gm >= N_NODES) continue;
        int gn = n0 + tx * 4;
        float4 o;
        o.x = acc[i][0] + bias[gn + 0];
        o.y = acc[i][1] + bias[gn + 1];
        o.z = acc[i][2] + bias[gn + 2];
        o.w = acc[i][3] + bias[gn + 3];
        *reinterpret_cast<float4*>(&out[(size_t)gm * 128 + gn]) = o;
    }
}

// ---------------------------------------------------------------------------
// CSR build (unchanged): histogram -> scan -> scatter to dst-sorted order.
// ---------------------------------------------------------------------------
__global__ __launch_bounds__(256) void hist_kernel(
    const int* __restrict__ ei, int* __restrict__ cnt)
{
    int e = blockIdx.x * 256 + threadIdx.x;
    if (e < E_EDGES) atomicAdd(&cnt[ei[E_EDGES + e]], 1);
}

__global__ __launch_bounds__(1024) void scan_kernel(
    const int* __restrict__ cnt, int* __restrict__ cur)
{
    __shared__ int part[1024];
    const int t = threadIdx.x;
    const int CH = (N_NODES + 1023) / 1024;
    const int base = t * CH;
    int s = 0;
    for (int i = 0; i < CH; ++i) {
        int idx = base + i;
        if (idx < N_NODES) s += cnt[idx];
    }
    part[t] = s;
    __syncthreads();
    int val = s;
    for (int d = 1; d < 1024; d <<= 1) {
        int other = (t >= d) ? part[t - d] : 0;
        __syncthreads();
        val += other;
        part[t] = val;
        __syncthreads();
    }
    int run = val - s;
    for (int i = 0; i < CH; ++i) {
        int idx = base + i;
        if (idx < N_NODES) {
            cur[idx] = run;
            run += cnt[idx];
        }
    }
}

__global__ __launch_bounds__(256) void scatter_kernel(
    const int* __restrict__ ei, int* __restrict__ cur, int* __restrict__ order)
{
    int e = blockIdx.x * 256 + threadIdx.x;
    if (e < E_EDGES) {
        int p = atomicAdd(&cur[ei[E_EDGES + e]], 1);
        order[p] = e;
    }
}

// ---------------------------------------------------------------------------
// pack_We: convert We (256x128 fp32) into bf16 hi/lo in MFMA B-fragment order.
// Fragment addressing for mfma_f32_16x16x32_bf16 B-operand:
//   B[k][n] with k = ks*32 + (lane>>4)*8 + j, n = ct*16 + (lane&15)
//   stored at bhi[((ks*8+ct)*64 + lane)*8 + j]  -> 16B/lane coalesced loads.
// 64 KB per array, L2-resident; runs once per launch (~µs).
// ---------------------------------------------------------------------------
__global__ __launch_bounds__(256) void pack_We(
    const float* __restrict__ We, u16* __restrict__ bhi, u16* __restrict__ blo)
{
    const int idx = blockIdx.x * 256 + threadIdx.x;   // (ks*8+ct)*64 + lane
    if (idx >= 4096) return;
    const int lane = idx & 63;
    const int tile = idx >> 6;
    const int ks = tile >> 3;
    const int ct = tile & 7;
    const int kb = ks * 32 + (lane >> 4) * 8;
    const int n  = ct * 16 + (lane & 15);
    u32 hw[4], lw[4];
    #pragma unroll
    for (int j = 0; j < 4; ++j) {
        float w0 = We[(size_t)(kb + 2 * j) * 128 + n];
        float w1 = We[(size_t)(kb + 2 * j + 1) * 128 + n];
        u16 h0 = f2bf(w0), h1 = f2bf(w1);
        u16 l0 = f2bf(w0 - bf2f(h0)), l1 = f2bf(w1 - bf2f(h1));
        hw[j] = (u32)h0 | ((u32)h1 << 16);
        lw[j] = (u32)l0 | ((u32)l1 << 16);
    }
    *reinterpret_cast<uint4*>(&bhi[idx * 8]) = make_uint4(hw[0], hw[1], hw[2], hw[3]);
    *reinterpret_cast<uint4*>(&blo[idx * 8]) = make_uint4(lw[0], lw[1], lw[2], lw[3]);
}

// ---------------------------------------------------------------------------
// K2: fused edge pipeline over dst-sorted edges, 32 edges / 256-thr block.
// e_vec GEMM now on the matrix pipe: attr split to bf16 hi/lo in LDS
// (XOR-swizzled rows, conflict-free ds_read_b128 A-fragments), We hi/lo
// fragments streamed from L2. 3-product split GEMM (hi*hi + lo*hi + hi*lo)
// in fp32 MFMA accumulators == fp32 accuracy (dropped term ~2^-18).
// Wave layout: w&1 = edge half (16 rows), w>>1 = head (64 cols).
// C/D layout: col = lane&15, row = (lane>>4)*4 + reg  -> each lane owns
// 4 consecutive sorted edges x 4 dims (stride 16), feeding the same
// shuffle-reduce softmax + run-merged atomics as before.
// ---------------------------------------------------------------------------
__global__ __launch_bounds__(256) void edge_kernel(
    const int* __restrict__ order,
    const int* __restrict__ ei,
    const float* __restrict__ last_update,
    const float* __restrict__ t,
    const float* __restrict__ msg,
    const float* __restrict__ Wt,
    const float* __restrict__ bt,
    const u16* __restrict__ Bhi,
    const u16* __restrict__ Blo,
    const float* __restrict__ q,
    const float* __restrict__ k,
    const float* __restrict__ v,
    float* __restrict__ agg,
    float* __restrict__ denom)
{
    __shared__ __align__(16) u16 sHi[32 * 256];
    __shared__ __align__(16) u16 sLo[32 * 256];
    __shared__ int sSrc[32], sDst[32], sEo[32];
    __shared__ float sRelT[32];

    const int tid = threadIdx.x;
    const int e0 = blockIdx.x * 32;

    if (tid < 32) {
        int e = order[e0 + tid];
        int s = ei[e];
        sEo[tid] = e;
        sSrc[tid] = s;
        sDst[tid] = ei[E_EDGES + e];
        sRelT[tid] = last_update[s] - t[e];
    }
    __syncthreads();

    // ---- stage attr = [cos(rel_t*Wt+bt) | msg] as bf16 hi/lo, swizzled.
    // thread -> (edge er, 8-col unit), 16B writes; byte ^= (er&7)<<4 matches
    // the 16B-granular read-side swizzle.
    {
        const int er = tid >> 3;
        const int c0 = (tid & 7) * 8;
        const float rt = sRelT[er];
        const int eo = sEo[er];
        char* hB = reinterpret_cast<char*>(sHi);
        char* lB = reinterpret_cast<char*>(sLo);
        #pragma unroll
        for (int p = 0; p < 4; ++p) {
            const int c = c0 + p * 64;
            float vals[8];
            if (p < 2) {
                const float4 w0 = *reinterpret_cast<const float4*>(&Wt[c]);
                const float4 w1 = *reinterpret_cast<const float4*>(&Wt[c + 4]);
                const float4 b0 = *reinterpret_cast<const float4*>(&bt[c]);
                const float4 b1 = *reinterpret_cast<const float4*>(&bt[c + 4]);
                vals[0] = cosf(fmaf(rt, w0.x, b0.x));
                vals[1] = cosf(fmaf(rt, w0.y, b0.y));
                vals[2] = cosf(fmaf(rt, w0.z, b0.z));
                vals[3] = cosf(fmaf(rt, w0.w, b0.w));
                vals[4] = cosf(fmaf(rt, w1.x, b1.x));
                vals[5] = cosf(fmaf(rt, w1.y, b1.y));
                vals[6] = cosf(fmaf(rt, w1.z, b1.z));
                vals[7] = cosf(fmaf(rt, w1.w, b1.w));
            } else {
                const float4 m0 = *reinterpret_cast<const float4*>(
                    &msg[(size_t)eo * 128 + (c - 128)]);
                const float4 m1 = *reinterpret_cast<const float4*>(
                    &msg[(size_t)eo * 128 + (c - 128) + 4]);
                vals[0] = m0.x; vals[1] = m0.y; vals[2] = m0.z; vals[3] = m0.w;
                vals[4] = m1.x; vals[5] = m1.y; vals[6] = m1.z; vals[7] = m1.w;
            }
            u32 hw[4], lw[4];
            #pragma unroll
            for (int j = 0; j < 4; ++j) {
                const u16 h0 = f2bf(vals[2 * j]);
                const u16 h1 = f2bf(vals[2 * j + 1]);
                const u16 l0 = f2bf(vals[2 * j] - bf2f(h0));
                const u16 l1 = f2bf(vals[2 * j + 1] - bf2f(h1));
                hw[j] = (u32)h0 | ((u32)h1 << 16);
                lw[j] = (u32)l0 | ((u32)l1 << 16);
            }
            const int off = (er * 512 + c * 2) ^ ((er & 7) << 4);
            *reinterpret_cast<uint4*>(hB + off) = make_uint4(hw[0], hw[1], hw[2], hw[3]);
            *reinterpret_cast<uint4*>(lB + off) = make_uint4(lw[0], lw[1], lw[2], lw[3]);
        }
    }
    __syncthreads();

    const int lane = tid & 63;
    const int wv = tid >> 6;
    const int eh = wv & 1;     // edge half: rows eh*16 .. +15
    const int hh = wv >> 1;    // head: cols hh*64 .. +63
    const int cl = lane & 15;
    const int g = lane >> 4;

    f32x4 acc[4] = {{0.f,0.f,0.f,0.f},{0.f,0.f,0.f,0.f},
                    {0.f,0.f,0.f,0.f},{0.f,0.f,0.f,0.f}};

    // ---- split-bf16 MFMA GEMM: 8 k-steps x 4 col-tiles x 3 products
    {
        const int row = eh * 16 + cl;             // A-frag row = lane&15
        const char* hB = reinterpret_cast<const char*>(sHi);
        const char* lB = reinterpret_cast<const char*>(sLo);
        const int rbase = row * 512;
        const int swz = (row & 7) << 4;
        #pragma unroll
        for (int ks = 0; ks < 8; ++ks) {
            const int off = (rbase + (ks * 32 + g * 8) * 2) ^ swz;
            const short8v ah = *reinterpret_cast<const short8v*>(hB + off);
            const short8v al = *reinterpret_cast<const short8v*>(lB + off);
            #pragma unroll
            for (int tc = 0; tc < 4; ++tc) {
                const int bi = ((ks * 8 + hh * 4 + tc) * 64 + lane) * 8;
                const short8v bh = *reinterpret_cast<const short8v*>(&Bhi[bi]);
                const short8v bl = *reinterpret_cast<const short8v*>(&Blo[bi]);
                acc[tc] = __builtin_amdgcn_mfma_f32_16x16x32_bf16(ah, bh, acc[tc], 0, 0, 0);
                acc[tc] = __builtin_amdgcn_mfma_f32_16x16x32_bf16(al, bh, acc[tc], 0, 0, 0);
                acc[tc] = __builtin_amdgcn_mfma_f32_16x16x32_bf16(ah, bl, acc[tc], 0, 0, 0);
            }
        }
    }

    // ---- attention: alpha = q[dst].(k[src]+e)/8 per head, 16-lane reduce
    float ex[4];
    int srcs[4], dsts[4];
    #pragma unroll
    for (int r = 0; r < 4; ++r) {
        const int er = eh * 16 + g * 4 + r;       // C row -> sorted edge
        const int s = sSrc[er];
        const int dd = sDst[er];
        srcs[r] = s; dsts[r] = dd;
        float p = 0.f;
        #pragma unroll
        for (int tc = 0; tc < 4; ++tc) {
            const int d = hh * 64 + tc * 16 + cl;
            p = fmaf(q[(size_t)dd * 128 + d], k[(size_t)s * 128 + d] + acc[tc][r], p);
        }
        p += __shfl_xor(p, 1);
        p += __shfl_xor(p, 2);
        p += __shfl_xor(p, 4);
        p += __shfl_xor(p, 8);
        ex[r] = expf(p * 0.125f);                 // 1/sqrt(64)
    }

    // denom: merge equal-dst runs (edges sorted by dst), one atomic per run
    if (cl == 0) {
        float dsum = ex[0];
        #pragma unroll
        for (int r = 1; r < 4; ++r) {
            if (dsts[r] == dsts[r - 1]) {
                dsum += ex[r];
            } else {
                atomicAdd(&denom[(size_t)dsts[r - 1] * 2 + hh], dsum);
                dsum = ex[r];
            }
        }
        atomicAdd(&denom[(size_t)dsts[3] * 2 + hh], dsum);
    }

    // agg: ex * (v[src] + e), run-merged atomics (4 dims/lane, stride 16)
    float run[4];
    int prevDst = dsts[0];
    #pragma unroll
    for (int r = 0; r < 4; ++r) {
        const int s = srcs[r];
        float cur[4];
        #pragma unroll
        for (int tc = 0; tc < 4; ++tc) {
            const int d = hh * 64 + tc * 16 + cl;
            cur[tc] = ex[r] * (v[(size_t)s * 128 + d] + acc[tc][r]);
        }
        if (r == 0) {
            #pragma unroll
            for (int tc = 0; tc < 4; ++tc) run[tc] = cur[tc];
        } else if (dsts[r] == prevDst) {
            #pragma unroll
            for (int tc = 0; tc < 4; ++tc) run[tc] += cur[tc];
        } else {
            float* ap = &agg[(size_t)prevDst * 128 + hh * 64 + cl];
            #pragma unroll
            for (int tc = 0; tc < 4; ++tc) atomicAdd(ap + tc * 16, run[tc]);
            #pragma unroll
            for (int tc = 0; tc < 4; ++tc) run[tc] = cur[tc];
            prevDst = dsts[r];
        }
    }
    {
        float* ap = &agg[(size_t)prevDst * 128 + hh * 64 + cl];
        #pragma unroll
        for (int tc = 0; tc < 4; ++tc) atomicAdd(ap + tc * 16, run[tc]);
    }
}

// ---------------------------------------------------------------------------
// K3: out = agg / denom + skip (skip already resident in out). Unchanged.
// ---------------------------------------------------------------------------
__global__ __launch_bounds__(256) void finalize(
    const float* __restrict__ agg, const float* __restrict__ denom,
    float* __restrict__ out)
{
    size_t base = ((size_t)blockIdx.x * 256 + threadIdx.x) * 4;
    if (base >= (size_t)N_NODES * 128) return;
    int n = (int)(base >> 7);
    int h = (int)((base >> 6) & 1);
    float dn = denom[(size_t)n * 2 + h];
    float inv = (dn > 0.f) ? (1.f / dn) : 0.f;
    float4 a = *reinterpret_cast<const float4*>(&agg[base]);
    float4 o = *reinterpret_cast<const float4*>(&out[base]);
    o.x += a.x * inv;
    o.y += a.y * inv;
    o.z += a.z * inv;
    o.w += a.w * inv;
    *reinterpret_cast<float4*>(&out[base]) = o;
}

extern "C" void kernel_launch(void* const* d_in, const int* in_sizes, int n_in,
                              void* d_out, int out_size, void* d_ws, size_t ws_size,
                              hipStream_t stream)
{
    const float* x   = (const float*)d_in[0];
    const float* lu  = (const float*)d_in[1];
    const int*   ei  = (const int*)d_in[2];
    const float* t   = (const float*)d_in[3];
    const float* msg = (const float*)d_in[4];
    const float* Wt  = (const float*)d_in[5];
    const float* bt  = (const float*)d_in[6];
    const float* Wq  = (const float*)d_in[7];
    const float* bq  = (const float*)d_in[8];
    const float* Wk  = (const float*)d_in[9];
    const float* bk  = (const float*)d_in[10];
    const float* Wv  = (const float*)d_in[11];
    const float* bv  = (const float*)d_in[12];
    const float* We  = (const float*)d_in[13];
    const float* Wsk = (const float*)d_in[14];
    const float* bsk = (const float*)d_in[15];
    float* out = (float*)d_out;

    float* q    = (float*)d_ws;
    float* k    = q   + (size_t)N_NODES * 128;
    float* v    = k   + (size_t)N_NODES * 128;
    float* agg  = v   + (size_t)N_NODES * 128;
    float* den  = agg + (size_t)N_NODES * 128;
    int*   cnt  = (int*)(den + (size_t)N_NODES * 2);
    int*   cur  = cnt + N_NODES;
    int*   order= cur + N_NODES;
    // cnt/cur are dead after scatter_kernel: reuse for the 64KB We fragment
    // arrays (16B-aligned by construction). pack_We runs after scatter.
    u16* Bhi = (u16*)cnt;
    u16* Blo = (u16*)cur;

    // zero agg + denom + cnt (contiguous)
    hipMemsetAsync(agg, 0,
                   ((size_t)N_NODES * 128 + (size_t)N_NODES * 2 + N_NODES) * sizeof(float),
                   stream);

    dim3 g1((N_NODES + 63) / 64, 2, 4);
    qkvs_gemm<<<g1, 256, 0, stream>>>(x, Wq, bq, Wk, bk, Wv, bv, Wsk, bsk,
                                      q, k, v, out);

    hist_kernel<<<dim3((E_EDGES + 255) / 256), 256, 0, stream>>>(ei, cnt);
    scan_kernel<<<dim3(1), 1024, 0, stream>>>(cnt, cur);
    scatter_kernel<<<dim3((E_EDGES + 255) / 256), 256, 0, stream>>>(ei, cur, order);

    pack_We<<<dim3(16), 256, 0, stream>>>(We, Bhi, Blo);

    edge_kernel<<<dim3(E_EDGES / 32), 256, 0, stream>>>(
        order, ei, lu, t, msg, Wt, bt, Bhi, Blo, q, k, v, agg, den);

    finalize<<<dim3((N_NODES * 128 / 4 + 255) / 256), 256, 0, stream>>>(agg, den, out);
}

// Round 2
// 1248.297 us; speedup vs baseline: 1.3546x; 1.0405x over previous
//
#include <hip/hip_runtime.h>
#include <math.h>

#define N_NODES 50000
#define E_EDGES 800000
#define D_DIM 128
#define H_HEADS 2
#define DH_DIM 64
#define C_DIM 256

typedef unsigned short u16;
typedef unsigned int u32;
typedef __attribute__((ext_vector_type(8))) short short8v;  // 8 bf16 (4 VGPRs)
typedef __attribute__((ext_vector_type(4))) float f32x4;

// bf16 round-to-nearest-even split helpers (Dekker: x = hi + lo exactly to ~2^-17)
static __device__ __forceinline__ u16 f2bf(float x) {
    union { float f; u32 u; } a; a.f = x;
    u32 r = a.u + 0x7fffu + ((a.u >> 16) & 1u);
    return (u16)(r >> 16);
}
static __device__ __forceinline__ float bf2f(u16 h) {
    union { u32 u; float f; } a; a.u = ((u32)h) << 16;
    return a.f;
}

// ---------------------------------------------------------------------------
// pack_W4: Wq/Wk/Wv/Wskip (128x128 fp32) -> bf16 hi/lo MFMA B-fragments.
// Layout: idx = ((z*4+ks)*8+ct)*64+lane, elems j: k=ks*32+(lane>>4)*8+j,
// n=ct*16+(lane&15). 128 KB hi + 128 KB lo, L2-resident.
// ---------------------------------------------------------------------------
__global__ __launch_bounds__(256) void pack_W4(
    const float* __restrict__ Wq, const float* __restrict__ Wk,
    const float* __restrict__ Wv, const float* __restrict__ Wsk,
    u16* __restrict__ whi, u16* __restrict__ wlo)
{
    const int idx = blockIdx.x * 256 + threadIdx.x;
    if (idx >= 8192) return;
    const int lane = idx & 63;
    const int ct = (idx >> 6) & 7;
    const int ks = (idx >> 9) & 3;
    const int z  = idx >> 11;
    const float* W = (z == 0) ? Wq : (z == 1) ? Wk : (z == 2) ? Wv : Wsk;
    const int kb = ks * 32 + (lane >> 4) * 8;
    const int n  = ct * 16 + (lane & 15);
    u32 hw[4], lw[4];
    #pragma unroll
    for (int j = 0; j < 4; ++j) {
        float w0 = W[(size_t)(kb + 2 * j) * 128 + n];
        float w1 = W[(size_t)(kb + 2 * j + 1) * 128 + n];
        u16 h0 = f2bf(w0), h1 = f2bf(w1);
        u16 l0 = f2bf(w0 - bf2f(h0)), l1 = f2bf(w1 - bf2f(h1));
        hw[j] = (u32)h0 | ((u32)h1 << 16);
        lw[j] = (u32)l0 | ((u32)l1 << 16);
    }
    *reinterpret_cast<uint4*>(&whi[idx * 8]) = make_uint4(hw[0], hw[1], hw[2], hw[3]);
    *reinterpret_cast<uint4*>(&wlo[idx * 8]) = make_uint4(lw[0], lw[1], lw[2], lw[3]);
}

// ---------------------------------------------------------------------------
// K1: q/k/v/skip = x @ W + b via split-bf16 MFMA (3-term: full fp32-accuracy).
// Block = 16 rows of x staged hi/lo in LDS (swizzled); wave wv computes the
// full 16x128 tile for weight z=wv. 3125 blocks.
// ---------------------------------------------------------------------------
__global__ __launch_bounds__(256, 4) void qkvs_mfma(
    const float* __restrict__ x,
    const u16* __restrict__ WBhi, const u16* __restrict__ WBlo,
    const float* __restrict__ bq, const float* __restrict__ bk,
    const float* __restrict__ bv, const float* __restrict__ bsk,
    float* __restrict__ qo, float* __restrict__ ko, float* __restrict__ vo,
    float* __restrict__ so)
{
    __shared__ __align__(16) u16 sXh[16 * 128];
    __shared__ __align__(16) u16 sXl[16 * 128];
    const int tid = threadIdx.x;
    const int m0 = blockIdx.x * 16;     // 3125*16 == 50000 exactly, no bounds

    {   // stage x tile: row = tid>>4, 8-col unit = tid&15 (coalesced float4 x2)
        const int row = tid >> 4;
        const int c8 = (tid & 15) * 8;
        const float4 a = *reinterpret_cast<const float4*>(&x[(size_t)(m0 + row) * 128 + c8]);
        const float4 b = *reinterpret_cast<const float4*>(&x[(size_t)(m0 + row) * 128 + c8 + 4]);
        const float vals[8] = {a.x, a.y, a.z, a.w, b.x, b.y, b.z, b.w};
        u32 hw[4], lw[4];
        #pragma unroll
        for (int j = 0; j < 4; ++j) {
            const u16 h0 = f2bf(vals[2 * j]);
            const u16 h1 = f2bf(vals[2 * j + 1]);
            const u16 l0 = f2bf(vals[2 * j] - bf2f(h0));
            const u16 l1 = f2bf(vals[2 * j + 1] - bf2f(h1));
            hw[j] = (u32)h0 | ((u32)h1 << 16);
            lw[j] = (u32)l0 | ((u32)l1 << 16);
        }
        const int off = (row * 256 + c8 * 2) ^ ((row & 15) << 4);
        *reinterpret_cast<uint4*>(reinterpret_cast<char*>(sXh) + off) =
            make_uint4(hw[0], hw[1], hw[2], hw[3]);
        *reinterpret_cast<uint4*>(reinterpret_cast<char*>(sXl) + off) =
            make_uint4(lw[0], lw[1], lw[2], lw[3]);
    }
    __syncthreads();

    const int lane = tid & 63;
    const int wv = tid >> 6;            // z: 0=q 1=k 2=v 3=skip
    const int cl = lane & 15;
    const int g = lane >> 4;

    f32x4 acc[8] = {};
    {
        const char* hB = reinterpret_cast<const char*>(sXh);
        const char* lB = reinterpret_cast<const char*>(sXl);
        const int rbase = cl * 256;
        const int swz = cl << 4;
        #pragma unroll
        for (int ks = 0; ks < 4; ++ks) {
            const int off = (rbase + ks * 64 + g * 16) ^ swz;
            const short8v ah = *reinterpret_cast<const short8v*>(hB + off);
            const short8v al = *reinterpret_cast<const short8v*>(lB + off);
            #pragma unroll
            for (int ct = 0; ct < 8; ++ct) {
                const int bi = (((wv * 4 + ks) * 8 + ct) * 64 + lane) * 8;
                const short8v bh = *reinterpret_cast<const short8v*>(&WBhi[bi]);
                const short8v bl = *reinterpret_cast<const short8v*>(&WBlo[bi]);
                acc[ct] = __builtin_amdgcn_mfma_f32_16x16x32_bf16(ah, bh, acc[ct], 0, 0, 0);
                acc[ct] = __builtin_amdgcn_mfma_f32_16x16x32_bf16(al, bh, acc[ct], 0, 0, 0);
                acc[ct] = __builtin_amdgcn_mfma_f32_16x16x32_bf16(ah, bl, acc[ct], 0, 0, 0);
            }
        }
    }

    const float* bias; float* out;
    switch (wv) {
        case 0: bias = bq;  out = qo; break;
        case 1: bias = bk;  out = ko; break;
        case 2: bias = bv;  out = vo; break;
        default: bias = bsk; out = so; break;
    }
    #pragma unroll
    for (int ct = 0; ct < 8; ++ct) {
        const int col = ct * 16 + cl;
        const float bb = bias[col];
        #pragma unroll
        for (int j = 0; j < 4; ++j) {
            const int row = g * 4 + j;
            out[(size_t)(m0 + row) * 128 + col] = acc[ct][j] + bb;
        }
    }
}

// ---------------------------------------------------------------------------
// CSR build (unchanged): histogram -> scan -> scatter to dst-sorted order.
// ---------------------------------------------------------------------------
__global__ __launch_bounds__(256) void hist_kernel(
    const int* __restrict__ ei, int* __restrict__ cnt)
{
    int e = blockIdx.x * 256 + threadIdx.x;
    if (e < E_EDGES) atomicAdd(&cnt[ei[E_EDGES + e]], 1);
}

__global__ __launch_bounds__(1024) void scan_kernel(
    const int* __restrict__ cnt, int* __restrict__ cur)
{
    __shared__ int part[1024];
    const int t = threadIdx.x;
    const int CH = (N_NODES + 1023) / 1024;
    const int base = t * CH;
    int s = 0;
    for (int i = 0; i < CH; ++i) {
        int idx = base + i;
        if (idx < N_NODES) s += cnt[idx];
    }
    part[t] = s;
    __syncthreads();
    int val = s;
    for (int d = 1; d < 1024; d <<= 1) {
        int other = (t >= d) ? part[t - d] : 0;
        __syncthreads();
        val += other;
        part[t] = val;
        __syncthreads();
    }
    int run = val - s;
    for (int i = 0; i < CH; ++i) {
        int idx = base + i;
        if (idx < N_NODES) {
            cur[idx] = run;
            run += cnt[idx];
        }
    }
}

__global__ __launch_bounds__(256) void scatter_kernel(
    const int* __restrict__ ei, int* __restrict__ cur, int* __restrict__ order)
{
    int e = blockIdx.x * 256 + threadIdx.x;
    if (e < E_EDGES) {
        int p = atomicAdd(&cur[ei[E_EDGES + e]], 1);
        order[p] = e;
    }
}

// ---------------------------------------------------------------------------
// pack_We: We (256x128 fp32) -> bf16 hi/lo MFMA B-fragments (as round 1).
// ---------------------------------------------------------------------------
__global__ __launch_bounds__(256) void pack_We(
    const float* __restrict__ We, u16* __restrict__ bhi, u16* __restrict__ blo)
{
    const int idx = blockIdx.x * 256 + threadIdx.x;   // (ks*8+ct)*64 + lane
    if (idx >= 4096) return;
    const int lane = idx & 63;
    const int tile = idx >> 6;
    const int ks = tile >> 3;
    const int ct = tile & 7;
    const int kb = ks * 32 + (lane >> 4) * 8;
    const int n  = ct * 16 + (lane & 15);
    u32 hw[4], lw[4];
    #pragma unroll
    for (int j = 0; j < 4; ++j) {
        float w0 = We[(size_t)(kb + 2 * j) * 128 + n];
        float w1 = We[(size_t)(kb + 2 * j + 1) * 128 + n];
        u16 h0 = f2bf(w0), h1 = f2bf(w1);
        u16 l0 = f2bf(w0 - bf2f(h0)), l1 = f2bf(w1 - bf2f(h1));
        hw[j] = (u32)h0 | ((u32)h1 << 16);
        lw[j] = (u32)l0 | ((u32)l1 << 16);
    }
    *reinterpret_cast<uint4*>(&bhi[idx * 8]) = make_uint4(hw[0], hw[1], hw[2], hw[3]);
    *reinterpret_cast<uint4*>(&blo[idx * 8]) = make_uint4(lw[0], lw[1], lw[2], lw[3]);
}

// ---------------------------------------------------------------------------
// K2: fused edge pipeline, dst-sorted, 32 edges / 256-thr block.
// Round-2 changes vs round-1:
//  * attr staged as bf16 HI ONLY (A-lo term dropped; err ~2e-3 << 0.03 floor)
//    -> LDS 33 KB -> 17 KB -> 8 blocks/CU (occupancy 44% -> ~90%)
//  * 2-term GEMM: ah*bh + ah*bl (64 MFMA/wave)
//  * __cosf/__expf fast transcendentals (args |x/2pi| < 512 HW range)
//  * full-row swizzle (row&15)<<4: conflict-free A-fragment ds_read_b128
//  * __launch_bounds__(256,8) pins VGPR<=64 so LDS is the occupancy limit
// ---------------------------------------------------------------------------
__global__ __launch_bounds__(256, 8) void edge_kernel(
    const int* __restrict__ order,
    const int* __restrict__ ei,
    const float* __restrict__ last_update,
    const float* __restrict__ t,
    const float* __restrict__ msg,
    const float* __restrict__ Wt,
    const float* __restrict__ bt,
    const u16* __restrict__ Bhi,
    const u16* __restrict__ Blo,
    const float* __restrict__ q,
    const float* __restrict__ k,
    const float* __restrict__ v,
    float* __restrict__ agg,
    float* __restrict__ denom)
{
    __shared__ __align__(16) u16 sHi[32 * 256];
    __shared__ int sSrc[32], sDst[32], sEo[32];
    __shared__ float sRelT[32];

    const int tid = threadIdx.x;
    const int e0 = blockIdx.x * 32;

    if (tid < 32) {
        int e = order[e0 + tid];
        int s = ei[e];
        sEo[tid] = e;
        sSrc[tid] = s;
        sDst[tid] = ei[E_EDGES + e];
        sRelT[tid] = last_update[s] - t[e];
    }
    __syncthreads();

    // ---- stage attr = [cos(rel_t*Wt+bt) | msg] as bf16 hi, swizzled
    {
        const int er = tid >> 3;
        const int c0 = (tid & 7) * 8;
        const float rt = sRelT[er];
        const int eo = sEo[er];
        char* hB = reinterpret_cast<char*>(sHi);
        #pragma unroll
        for (int p = 0; p < 4; ++p) {
            const int c = c0 + p * 64;
            float vals[8];
            if (p < 2) {
                const float4 w0 = *reinterpret_cast<const float4*>(&Wt[c]);
                const float4 w1 = *reinterpret_cast<const float4*>(&Wt[c + 4]);
                const float4 b0 = *reinterpret_cast<const float4*>(&bt[c]);
                const float4 b1 = *reinterpret_cast<const float4*>(&bt[c + 4]);
                vals[0] = __cosf(fmaf(rt, w0.x, b0.x));
                vals[1] = __cosf(fmaf(rt, w0.y, b0.y));
                vals[2] = __cosf(fmaf(rt, w0.z, b0.z));
                vals[3] = __cosf(fmaf(rt, w0.w, b0.w));
                vals[4] = __cosf(fmaf(rt, w1.x, b1.x));
                vals[5] = __cosf(fmaf(rt, w1.y, b1.y));
                vals[6] = __cosf(fmaf(rt, w1.z, b1.z));
                vals[7] = __cosf(fmaf(rt, w1.w, b1.w));
            } else {
                const float4 m0 = *reinterpret_cast<const float4*>(
                    &msg[(size_t)eo * 128 + (c - 128)]);
                const float4 m1 = *reinterpret_cast<const float4*>(
                    &msg[(size_t)eo * 128 + (c - 128) + 4]);
                vals[0] = m0.x; vals[1] = m0.y; vals[2] = m0.z; vals[3] = m0.w;
                vals[4] = m1.x; vals[5] = m1.y; vals[6] = m1.z; vals[7] = m1.w;
            }
            u32 hw[4];
            #pragma unroll
            for (int j = 0; j < 4; ++j)
                hw[j] = (u32)f2bf(vals[2 * j]) | ((u32)f2bf(vals[2 * j + 1]) << 16);
            const int off = (er * 512 + c * 2) ^ ((er & 15) << 4);
            *reinterpret_cast<uint4*>(hB + off) = make_uint4(hw[0], hw[1], hw[2], hw[3]);
        }
    }
    __syncthreads();

    const int lane = tid & 63;
    const int wv = tid >> 6;
    const int eh = wv & 1;     // edge half: rows eh*16 .. +15
    const int hh = wv >> 1;    // head: cols hh*64 .. +63
    const int cl = lane & 15;
    const int g = lane >> 4;

    f32x4 acc[4] = {{0.f,0.f,0.f,0.f},{0.f,0.f,0.f,0.f},
                    {0.f,0.f,0.f,0.f},{0.f,0.f,0.f,0.f}};

    // ---- 2-term split MFMA: 8 k-steps x 4 col-tiles x (ah*bh + ah*bl)
    {
        const int row = eh * 16 + cl;
        const char* hB = reinterpret_cast<const char*>(sHi);
        const int rbase = row * 512;
        const int swz = (row & 15) << 4;
        #pragma unroll
        for (int ks = 0; ks < 8; ++ks) {
            const int off = (rbase + ks * 64 + g * 16) ^ swz;
            const short8v ah = *reinterpret_cast<const short8v*>(hB + off);
            #pragma unroll
            for (int tc = 0; tc < 4; ++tc) {
                const int bi = ((ks * 8 + hh * 4 + tc) * 64 + lane) * 8;
                const short8v bh = *reinterpret_cast<const short8v*>(&Bhi[bi]);
                const short8v bl = *reinterpret_cast<const short8v*>(&Blo[bi]);
                acc[tc] = __builtin_amdgcn_mfma_f32_16x16x32_bf16(ah, bh, acc[tc], 0, 0, 0);
                acc[tc] = __builtin_amdgcn_mfma_f32_16x16x32_bf16(ah, bl, acc[tc], 0, 0, 0);
            }
        }
    }

    // ---- attention: alpha = q[dst].(k[src]+e)/8 per head, 16-lane reduce
    float ex[4];
    int srcs[4], dsts[4];
    #pragma unroll
    for (int r = 0; r < 4; ++r) {
        const int er = eh * 16 + g * 4 + r;
        const int s = sSrc[er];
        const int dd = sDst[er];
        srcs[r] = s; dsts[r] = dd;
        float p = 0.f;
        #pragma unroll
        for (int tc = 0; tc < 4; ++tc) {
            const int d = hh * 64 + tc * 16 + cl;
            p = fmaf(q[(size_t)dd * 128 + d], k[(size_t)s * 128 + d] + acc[tc][r], p);
        }
        p += __shfl_xor(p, 1);
        p += __shfl_xor(p, 2);
        p += __shfl_xor(p, 4);
        p += __shfl_xor(p, 8);
        ex[r] = __expf(p * 0.125f);               // 1/sqrt(64)
    }

    // denom: merge equal-dst runs, one atomic per run
    if (cl == 0) {
        float dsum = ex[0];
        #pragma unroll
        for (int r = 1; r < 4; ++r) {
            if (dsts[r] == dsts[r - 1]) {
                dsum += ex[r];
            } else {
                atomicAdd(&denom[(size_t)dsts[r - 1] * 2 + hh], dsum);
                dsum = ex[r];
            }
        }
        atomicAdd(&denom[(size_t)dsts[3] * 2 + hh], dsum);
    }

    // agg: ex * (v[src] + e), run-merged atomics (4 dims/lane, stride 16)
    float run[4];
    int prevDst = dsts[0];
    #pragma unroll
    for (int r = 0; r < 4; ++r) {
        const int s = srcs[r];
        float cur[4];
        #pragma unroll
        for (int tc = 0; tc < 4; ++tc) {
            const int d = hh * 64 + tc * 16 + cl;
            cur[tc] = ex[r] * (v[(size_t)s * 128 + d] + acc[tc][r]);
        }
        if (r == 0) {
            #pragma unroll
            for (int tc = 0; tc < 4; ++tc) run[tc] = cur[tc];
        } else if (dsts[r] == prevDst) {
            #pragma unroll
            for (int tc = 0; tc < 4; ++tc) run[tc] += cur[tc];
        } else {
            float* ap = &agg[(size_t)prevDst * 128 + hh * 64 + cl];
            #pragma unroll
            for (int tc = 0; tc < 4; ++tc) atomicAdd(ap + tc * 16, run[tc]);
            #pragma unroll
            for (int tc = 0; tc < 4; ++tc) run[tc] = cur[tc];
            prevDst = dsts[r];
        }
    }
    {
        float* ap = &agg[(size_t)prevDst * 128 + hh * 64 + cl];
        #pragma unroll
        for (int tc = 0; tc < 4; ++tc) atomicAdd(ap + tc * 16, run[tc]);
    }
}

// ---------------------------------------------------------------------------
// K3: out = agg / denom + skip (skip already resident in out). Unchanged.
// ---------------------------------------------------------------------------
__global__ __launch_bounds__(256) void finalize(
    const float* __restrict__ agg, const float* __restrict__ denom,
    float* __restrict__ out)
{
    size_t base = ((size_t)blockIdx.x * 256 + threadIdx.x) * 4;
    if (base >= (size_t)N_NODES * 128) return;
    int n = (int)(base >> 7);
    int h = (int)((base >> 6) & 1);
    float dn = denom[(size_t)n * 2 + h];
    float inv = (dn > 0.f) ? (1.f / dn) : 0.f;
    float4 a = *reinterpret_cast<const float4*>(&agg[base]);
    float4 o = *reinterpret_cast<const float4*>(&out[base]);
    o.x += a.x * inv;
    o.y += a.y * inv;
    o.z += a.z * inv;
    o.w += a.w * inv;
    *reinterpret_cast<float4*>(&out[base]) = o;
}

extern "C" void kernel_launch(void* const* d_in, const int* in_sizes, int n_in,
                              void* d_out, int out_size, void* d_ws, size_t ws_size,
                              hipStream_t stream)
{
    const float* x   = (const float*)d_in[0];
    const float* lu  = (const float*)d_in[1];
    const int*   ei  = (const int*)d_in[2];
    const float* t   = (const float*)d_in[3];
    const float* msg = (const float*)d_in[4];
    const float* Wt  = (const float*)d_in[5];
    const float* bt  = (const float*)d_in[6];
    const float* Wq  = (const float*)d_in[7];
    const float* bq  = (const float*)d_in[8];
    const float* Wk  = (const float*)d_in[9];
    const float* bk  = (const float*)d_in[10];
    const float* Wv  = (const float*)d_in[11];
    const float* bv  = (const float*)d_in[12];
    const float* We  = (const float*)d_in[13];
    const float* Wsk = (const float*)d_in[14];
    const float* bsk = (const float*)d_in[15];
    float* out = (float*)d_out;

    float* q    = (float*)d_ws;
    float* k    = q   + (size_t)N_NODES * 128;
    float* v    = k   + (size_t)N_NODES * 128;
    float* agg  = v   + (size_t)N_NODES * 128;
    float* den  = agg + (size_t)N_NODES * 128;
    int*   cnt  = (int*)(den + (size_t)N_NODES * 2);
    int*   cur  = cnt + N_NODES;
    int*   order= cur + N_NODES;
    // cnt (200 KB) is dead after scan_kernel, cur after scatter_kernel.
    // Reuse: cnt <- Bhi (64 KB) + WBhi (128 KB); cur <- Blo + WBlo. 192<=200 KB.
    u16* Bhi  = (u16*)cnt;
    u16* Blo  = (u16*)cur;
    u16* WBhi = Bhi + 32768;
    u16* WBlo = Blo + 32768;

    // zero agg + denom + cnt (contiguous)
    hipMemsetAsync(agg, 0,
                   ((size_t)N_NODES * 128 + (size_t)N_NODES * 2 + N_NODES) * sizeof(float),
                   stream);

    hist_kernel<<<dim3((E_EDGES + 255) / 256), 256, 0, stream>>>(ei, cnt);
    scan_kernel<<<dim3(1), 1024, 0, stream>>>(cnt, cur);
    scatter_kernel<<<dim3((E_EDGES + 255) / 256), 256, 0, stream>>>(ei, cur, order);

    pack_We<<<dim3(16), 256, 0, stream>>>(We, Bhi, Blo);
    pack_W4<<<dim3(32), 256, 0, stream>>>(Wq, Wk, Wv, Wsk, WBhi, WBlo);

    qkvs_mfma<<<dim3(N_NODES / 16), 256, 0, stream>>>(
        x, WBhi, WBlo, bq, bk, bv, bsk, q, k, v, out);

    edge_kernel<<<dim3(E_EDGES / 32), 256, 0, stream>>>(
        order, ei, lu, t, msg, Wt, bt, Bhi, Blo, q, k, v, agg, den);

    finalize<<<dim3((N_NODES * 128 / 4 + 255) / 256), 256, 0, stream>>>(agg, den, out);
}

// Round 3
// 1233.647 us; speedup vs baseline: 1.3707x; 1.0119x over previous
//
#include <hip/hip_runtime.h>
#include <math.h>

#define N_NODES 50000
#define E_EDGES 800000
#define D_DIM 128
#define H_HEADS 2
#define DH_DIM 64
#define C_DIM 256

typedef unsigned short u16;
typedef unsigned int u32;
typedef __attribute__((ext_vector_type(8))) short short8v;  // 8 bf16 (4 VGPRs)
typedef __attribute__((ext_vector_type(4))) float f32x4;

// bf16 round-to-nearest-even split helpers (Dekker: x = hi + lo exactly to ~2^-17)
static __device__ __forceinline__ u16 f2bf(float x) {
    union { float f; u32 u; } a; a.f = x;
    u32 r = a.u + 0x7fffu + ((a.u >> 16) & 1u);
    return (u16)(r >> 16);
}
static __device__ __forceinline__ float bf2f(u16 h) {
    union { u32 u; float f; } a; a.u = ((u32)h) << 16;
    return a.f;
}

// ---------------------------------------------------------------------------
// pack_weights: one kernel packs We (256x128) and Wq/Wk/Wv/Wskip (128x128)
// into bf16 hi/lo MFMA B-fragment order.
//   We:  idx in [0,4096):  ks=tile>>3 (K=256), ct=tile&7
//   W4:  idx2=idx-4096 in [0,8192): z=idx2>>11, ks=(idx2>>9)&3, ct=(idx2>>6)&7
// Element j of fragment: k = ks*32 + (lane>>4)*8 + j, n = ct*16 + (lane&15).
// ---------------------------------------------------------------------------
__global__ __launch_bounds__(256) void pack_weights(
    const float* __restrict__ We,
    const float* __restrict__ Wq, const float* __restrict__ Wk,
    const float* __restrict__ Wv, const float* __restrict__ Wsk,
    u16* __restrict__ bhi, u16* __restrict__ blo,
    u16* __restrict__ whi, u16* __restrict__ wlo)
{
    const int idx = blockIdx.x * 256 + threadIdx.x;
    if (idx >= 12288) return;
    const float* W; u16* oh; u16* ol; int kb, n, slot;
    if (idx < 4096) {
        const int lane = idx & 63;
        const int tile = idx >> 6;
        kb = (tile >> 3) * 32 + (lane >> 4) * 8;
        n  = (tile & 7) * 16 + (lane & 15);
        W = We; oh = bhi; ol = blo; slot = idx;
    } else {
        const int idx2 = idx - 4096;
        const int lane = idx2 & 63;
        const int ct = (idx2 >> 6) & 7;
        const int ks = (idx2 >> 9) & 3;
        const int z  = idx2 >> 11;
        W = (z == 0) ? Wq : (z == 1) ? Wk : (z == 2) ? Wv : Wsk;
        kb = ks * 32 + (lane >> 4) * 8;
        n  = ct * 16 + (lane & 15);
        oh = whi; ol = wlo; slot = idx2;
    }
    u32 hw[4], lw[4];
    #pragma unroll
    for (int j = 0; j < 4; ++j) {
        float w0 = W[(size_t)(kb + 2 * j) * 128 + n];
        float w1 = W[(size_t)(kb + 2 * j + 1) * 128 + n];
        u16 h0 = f2bf(w0), h1 = f2bf(w1);
        u16 l0 = f2bf(w0 - bf2f(h0)), l1 = f2bf(w1 - bf2f(h1));
        hw[j] = (u32)h0 | ((u32)h1 << 16);
        lw[j] = (u32)l0 | ((u32)l1 << 16);
    }
    *reinterpret_cast<uint4*>(&oh[(size_t)slot * 8]) = make_uint4(hw[0], hw[1], hw[2], hw[3]);
    *reinterpret_cast<uint4*>(&ol[(size_t)slot * 8]) = make_uint4(lw[0], lw[1], lw[2], lw[3]);
}

// ---------------------------------------------------------------------------
// K1: q/k/v/skip = x @ W + b via split-bf16 MFMA (3-term: fp32 accuracy).
// Block = 16 rows of x staged hi/lo in LDS (swizzled); wave wv owns weight z.
// Round-3: B-fragments pulled into register arrays per k-step (8 loads in
// flight) instead of load-wait-use — MLP through the L2-resident weights.
// ---------------------------------------------------------------------------
__global__ __launch_bounds__(256, 4) void qkvs_mfma(
    const float* __restrict__ x,
    const u16* __restrict__ WBhi, const u16* __restrict__ WBlo,
    const float* __restrict__ bq, const float* __restrict__ bk,
    const float* __restrict__ bv, const float* __restrict__ bsk,
    float* __restrict__ qo, float* __restrict__ ko, float* __restrict__ vo,
    float* __restrict__ so)
{
    __shared__ __align__(16) u16 sXh[16 * 128];
    __shared__ __align__(16) u16 sXl[16 * 128];
    const int tid = threadIdx.x;
    const int m0 = blockIdx.x * 16;     // 3125*16 == 50000 exactly

    {   // stage x tile: row = tid>>4, 8-col unit = tid&15
        const int row = tid >> 4;
        const int c8 = (tid & 15) * 8;
        const float4 a = *reinterpret_cast<const float4*>(&x[(size_t)(m0 + row) * 128 + c8]);
        const float4 b = *reinterpret_cast<const float4*>(&x[(size_t)(m0 + row) * 128 + c8 + 4]);
        const float vals[8] = {a.x, a.y, a.z, a.w, b.x, b.y, b.z, b.w};
        u32 hw[4], lw[4];
        #pragma unroll
        for (int j = 0; j < 4; ++j) {
            const u16 h0 = f2bf(vals[2 * j]);
            const u16 h1 = f2bf(vals[2 * j + 1]);
            const u16 l0 = f2bf(vals[2 * j] - bf2f(h0));
            const u16 l1 = f2bf(vals[2 * j + 1] - bf2f(h1));
            hw[j] = (u32)h0 | ((u32)h1 << 16);
            lw[j] = (u32)l0 | ((u32)l1 << 16);
        }
        const int off = (row * 256 + c8 * 2) ^ ((row & 15) << 4);
        *reinterpret_cast<uint4*>(reinterpret_cast<char*>(sXh) + off) =
            make_uint4(hw[0], hw[1], hw[2], hw[3]);
        *reinterpret_cast<uint4*>(reinterpret_cast<char*>(sXl) + off) =
            make_uint4(lw[0], lw[1], lw[2], lw[3]);
    }
    __syncthreads();

    const int lane = tid & 63;
    const int wv = tid >> 6;            // z: 0=q 1=k 2=v 3=skip
    const int cl = lane & 15;
    const int g = lane >> 4;

    f32x4 acc[8] = {};
    {
        const char* hB = reinterpret_cast<const char*>(sXh);
        const char* lB = reinterpret_cast<const char*>(sXl);
        const int rbase = cl * 256;
        const int swz = cl << 4;
        #pragma unroll
        for (int ks = 0; ks < 4; ++ks) {
            const int off = (rbase + ks * 64 + g * 16) ^ swz;
            const short8v ah = *reinterpret_cast<const short8v*>(hB + off);
            const short8v al = *reinterpret_cast<const short8v*>(lB + off);
            short8v bh[8], bl[8];
            #pragma unroll
            for (int ct = 0; ct < 8; ++ct) {
                const int bi = (((wv * 4 + ks) * 8 + ct) * 64 + lane) * 8;
                bh[ct] = *reinterpret_cast<const short8v*>(&WBhi[bi]);
                bl[ct] = *reinterpret_cast<const short8v*>(&WBlo[bi]);
            }
            #pragma unroll
            for (int ct = 0; ct < 8; ++ct) {
                acc[ct] = __builtin_amdgcn_mfma_f32_16x16x32_bf16(ah, bh[ct], acc[ct], 0, 0, 0);
                acc[ct] = __builtin_amdgcn_mfma_f32_16x16x32_bf16(al, bh[ct], acc[ct], 0, 0, 0);
                acc[ct] = __builtin_amdgcn_mfma_f32_16x16x32_bf16(ah, bl[ct], acc[ct], 0, 0, 0);
            }
        }
    }

    const float* bias; float* out;
    switch (wv) {
        case 0: bias = bq;  out = qo; break;
        case 1: bias = bk;  out = ko; break;
        case 2: bias = bv;  out = vo; break;
        default: bias = bsk; out = so; break;
    }
    #pragma unroll
    for (int ct = 0; ct < 8; ++ct) {
        const int col = ct * 16 + cl;
        const float bb = bias[col];
        #pragma unroll
        for (int j = 0; j < 4; ++j) {
            const int row = g * 4 + j;
            out[(size_t)(m0 + row) * 128 + col] = acc[ct][j] + bb;
        }
    }
}

// ---------------------------------------------------------------------------
// CSR build (unchanged): histogram -> scan -> scatter to dst-sorted order.
// ---------------------------------------------------------------------------
__global__ __launch_bounds__(256) void hist_kernel(
    const int* __restrict__ ei, int* __restrict__ cnt)
{
    int e = blockIdx.x * 256 + threadIdx.x;
    if (e < E_EDGES) atomicAdd(&cnt[ei[E_EDGES + e]], 1);
}

__global__ __launch_bounds__(1024) void scan_kernel(
    const int* __restrict__ cnt, int* __restrict__ cur)
{
    __shared__ int part[1024];
    const int t = threadIdx.x;
    const int CH = (N_NODES + 1023) / 1024;
    const int base = t * CH;
    int s = 0;
    for (int i = 0; i < CH; ++i) {
        int idx = base + i;
        if (idx < N_NODES) s += cnt[idx];
    }
    part[t] = s;
    __syncthreads();
    int val = s;
    for (int d = 1; d < 1024; d <<= 1) {
        int other = (t >= d) ? part[t - d] : 0;
        __syncthreads();
        val += other;
        part[t] = val;
        __syncthreads();
    }
    int run = val - s;
    for (int i = 0; i < CH; ++i) {
        int idx = base + i;
        if (idx < N_NODES) {
            cur[idx] = run;
            run += cnt[idx];
        }
    }
}

__global__ __launch_bounds__(256) void scatter_kernel(
    const int* __restrict__ ei, int* __restrict__ cur, int* __restrict__ order)
{
    int e = blockIdx.x * 256 + threadIdx.x;
    if (e < E_EDGES) {
        int p = atomicAdd(&cur[ei[E_EDGES + e]], 1);
        order[p] = e;
    }
}

// ---------------------------------------------------------------------------
// K2: fused edge pipeline, dst-sorted, 32 edges / 256-thr block.
// Round-3 changes (MLP-focused, logic identical to round 2):
//  * __launch_bounds__(256,4): VGPR cap 32 -> 128 (round-2's 32-VGPR pin
//    serialized all scattered loads -> latency-bound at 86% occupancy)
//  * q/k/v rows prefetched into 48 registers right after the header barrier;
//    their ~600cy latency hides under cos-staging + GEMM
//  * vmcnt retires in issue order -> msg loads issued BEFORE the prefetch,
//    and Wt/bt staged to LDS by header threads so the cos phase does no VMEM
//    (otherwise any later wait would drain the prefetch)
//  * B-fragments per k-step loaded into register arrays (8 x 16B in flight)
// ---------------------------------------------------------------------------
__global__ __launch_bounds__(256, 4) void edge_kernel(
    const int* __restrict__ order,
    const int* __restrict__ ei,
    const float* __restrict__ last_update,
    const float* __restrict__ t,
    const float* __restrict__ msg,
    const float* __restrict__ Wt,
    const float* __restrict__ bt,
    const u16* __restrict__ Bhi,
    const u16* __restrict__ Blo,
    const float* __restrict__ q,
    const float* __restrict__ k,
    const float* __restrict__ v,
    float* __restrict__ agg,
    float* __restrict__ denom)
{
    __shared__ __align__(16) u16 sHi[32 * 256];
    __shared__ int sSrc[32], sDst[32], sEo[32];
    __shared__ float sRelT[32];
    __shared__ __align__(16) float sWt[128], sBt[128];

    const int tid = threadIdx.x;
    const int e0 = blockIdx.x * 32;

    if (tid < 32) {
        int e = order[e0 + tid];
        int s = ei[e];
        sEo[tid] = e;
        sSrc[tid] = s;
        sDst[tid] = ei[E_EDGES + e];
        sRelT[tid] = last_update[s] - t[e];
    } else if (tid < 64) {
        const int i = (tid - 32) * 4;
        *reinterpret_cast<float4*>(&sWt[i]) = *reinterpret_cast<const float4*>(&Wt[i]);
    } else if (tid < 96) {
        const int i = (tid - 64) * 4;
        *reinterpret_cast<float4*>(&sBt[i]) = *reinterpret_cast<const float4*>(&bt[i]);
    }
    __syncthreads();

    const int lane = tid & 63;
    const int wv = tid >> 6;
    const int eh = wv & 1;     // edge half: rows eh*16 .. +15
    const int hh = wv >> 1;    // head: cols hh*64 .. +63
    const int cl = lane & 15;
    const int g = lane >> 4;

    // ---- (1) msg loads for this thread's staging slice (issued first)
    const int er = tid >> 3;
    const int c0 = (tid & 7) * 8;
    const int eo = sEo[er];
    const float4 mA0 = *reinterpret_cast<const float4*>(&msg[(size_t)eo * 128 + c0]);
    const float4 mA1 = *reinterpret_cast<const float4*>(&msg[(size_t)eo * 128 + c0 + 4]);
    const float4 mB0 = *reinterpret_cast<const float4*>(&msg[(size_t)eo * 128 + c0 + 64]);
    const float4 mB1 = *reinterpret_cast<const float4*>(&msg[(size_t)eo * 128 + c0 + 68]);

    // ---- (2) prefetch q/k/v rows for this lane's 4 edges (48 regs in flight)
    int srcs[4], dsts[4];
    #pragma unroll
    for (int r = 0; r < 4; ++r) {
        const int e2 = eh * 16 + g * 4 + r;
        srcs[r] = sSrc[e2];
        dsts[r] = sDst[e2];
    }
    float qr[4][4], kr[4][4], vr[4][4];
    #pragma unroll
    for (int r = 0; r < 4; ++r) {
        #pragma unroll
        for (int tc = 0; tc < 4; ++tc) {
            const int d = hh * 64 + tc * 16 + cl;
            qr[r][tc] = q[(size_t)dsts[r] * 128 + d];
            kr[r][tc] = k[(size_t)srcs[r] * 128 + d];
            vr[r][tc] = v[(size_t)srcs[r] * 128 + d];
        }
    }

    // ---- (3) pack+write msg halves (waits only on the msg loads), then
    // ---- (4) cos halves from LDS tables (no VMEM -> prefetch stays in flight)
    {
        char* hB = reinterpret_cast<char*>(sHi);
        const int swz = (er & 15) << 4;
        {
            u32 hw[4];
            hw[0] = (u32)f2bf(mA0.x) | ((u32)f2bf(mA0.y) << 16);
            hw[1] = (u32)f2bf(mA0.z) | ((u32)f2bf(mA0.w) << 16);
            hw[2] = (u32)f2bf(mA1.x) | ((u32)f2bf(mA1.y) << 16);
            hw[3] = (u32)f2bf(mA1.z) | ((u32)f2bf(mA1.w) << 16);
            const int off = (er * 512 + (128 + c0) * 2) ^ swz;
            *reinterpret_cast<uint4*>(hB + off) = make_uint4(hw[0], hw[1], hw[2], hw[3]);
        }
        {
            u32 hw[4];
            hw[0] = (u32)f2bf(mB0.x) | ((u32)f2bf(mB0.y) << 16);
            hw[1] = (u32)f2bf(mB0.z) | ((u32)f2bf(mB0.w) << 16);
            hw[2] = (u32)f2bf(mB1.x) | ((u32)f2bf(mB1.y) << 16);
            hw[3] = (u32)f2bf(mB1.z) | ((u32)f2bf(mB1.w) << 16);
            const int off = (er * 512 + (192 + c0) * 2) ^ swz;
            *reinterpret_cast<uint4*>(hB + off) = make_uint4(hw[0], hw[1], hw[2], hw[3]);
        }
        const float rt = sRelT[er];
        #pragma unroll
        for (int p = 0; p < 2; ++p) {
            const int c = c0 + p * 64;
            const float4 w0 = *reinterpret_cast<const float4*>(&sWt[c]);
            const float4 w1 = *reinterpret_cast<const float4*>(&sWt[c + 4]);
            const float4 b0 = *reinterpret_cast<const float4*>(&sBt[c]);
            const float4 b1 = *reinterpret_cast<const float4*>(&sBt[c + 4]);
            float vals[8];
            vals[0] = __cosf(fmaf(rt, w0.x, b0.x));
            vals[1] = __cosf(fmaf(rt, w0.y, b0.y));
            vals[2] = __cosf(fmaf(rt, w0.z, b0.z));
            vals[3] = __cosf(fmaf(rt, w0.w, b0.w));
            vals[4] = __cosf(fmaf(rt, w1.x, b1.x));
            vals[5] = __cosf(fmaf(rt, w1.y, b1.y));
            vals[6] = __cosf(fmaf(rt, w1.z, b1.z));
            vals[7] = __cosf(fmaf(rt, w1.w, b1.w));
            u32 hw[4];
            #pragma unroll
            for (int j = 0; j < 4; ++j)
                hw[j] = (u32)f2bf(vals[2 * j]) | ((u32)f2bf(vals[2 * j + 1]) << 16);
            const int off = (er * 512 + c * 2) ^ swz;
            *reinterpret_cast<uint4*>(hB + off) = make_uint4(hw[0], hw[1], hw[2], hw[3]);
        }
    }
    __syncthreads();

    f32x4 acc[4] = {{0.f,0.f,0.f,0.f},{0.f,0.f,0.f,0.f},
                    {0.f,0.f,0.f,0.f},{0.f,0.f,0.f,0.f}};

    // ---- 2-term split MFMA: 8 k-steps x 4 col-tiles x (ah*bh + ah*bl)
    {
        const int row = eh * 16 + cl;
        const char* hB = reinterpret_cast<const char*>(sHi);
        const int rbase = row * 512;
        const int swz = (row & 15) << 4;
        #pragma unroll
        for (int ks = 0; ks < 8; ++ks) {
            const int off = (rbase + ks * 64 + g * 16) ^ swz;
            const short8v ah = *reinterpret_cast<const short8v*>(hB + off);
            short8v bh[4], bl[4];
            #pragma unroll
            for (int tc = 0; tc < 4; ++tc) {
                const int bi = ((ks * 8 + hh * 4 + tc) * 64 + lane) * 8;
                bh[tc] = *reinterpret_cast<const short8v*>(&Bhi[bi]);
                bl[tc] = *reinterpret_cast<const short8v*>(&Blo[bi]);
            }
            #pragma unroll
            for (int tc = 0; tc < 4; ++tc) {
                acc[tc] = __builtin_amdgcn_mfma_f32_16x16x32_bf16(ah, bh[tc], acc[tc], 0, 0, 0);
                acc[tc] = __builtin_amdgcn_mfma_f32_16x16x32_bf16(ah, bl[tc], acc[tc], 0, 0, 0);
            }
        }
    }

    // ---- attention: alpha = q[dst].(k[src]+e)/8 per head, 16-lane reduce
    float ex[4];
    #pragma unroll
    for (int r = 0; r < 4; ++r) {
        float p = 0.f;
        #pragma unroll
        for (int tc = 0; tc < 4; ++tc)
            p = fmaf(qr[r][tc], kr[r][tc] + acc[tc][r], p);
        p += __shfl_xor(p, 1);
        p += __shfl_xor(p, 2);
        p += __shfl_xor(p, 4);
        p += __shfl_xor(p, 8);
        ex[r] = __expf(p * 0.125f);               // 1/sqrt(64)
    }

    // denom: merge equal-dst runs, one atomic per run
    if (cl == 0) {
        float dsum = ex[0];
        #pragma unroll
        for (int r = 1; r < 4; ++r) {
            if (dsts[r] == dsts[r - 1]) {
                dsum += ex[r];
            } else {
                atomicAdd(&denom[(size_t)dsts[r - 1] * 2 + hh], dsum);
                dsum = ex[r];
            }
        }
        atomicAdd(&denom[(size_t)dsts[3] * 2 + hh], dsum);
    }

    // agg: ex * (v[src] + e), run-merged atomics (4 dims/lane, stride 16)
    float run[4];
    int prevDst = dsts[0];
    #pragma unroll
    for (int r = 0; r < 4; ++r) {
        float cur[4];
        #pragma unroll
        for (int tc = 0; tc < 4; ++tc)
            cur[tc] = ex[r] * (vr[r][tc] + acc[tc][r]);
        if (r == 0) {
            #pragma unroll
            for (int tc = 0; tc < 4; ++tc) run[tc] = cur[tc];
        } else if (dsts[r] == prevDst) {
            #pragma unroll
            for (int tc = 0; tc < 4; ++tc) run[tc] += cur[tc];
        } else {
            float* ap = &agg[(size_t)prevDst * 128 + hh * 64 + cl];
            #pragma unroll
            for (int tc = 0; tc < 4; ++tc) atomicAdd(ap + tc * 16, run[tc]);
            #pragma unroll
            for (int tc = 0; tc < 4; ++tc) run[tc] = cur[tc];
            prevDst = dsts[r];
        }
    }
    {
        float* ap = &agg[(size_t)prevDst * 128 + hh * 64 + cl];
        #pragma unroll
        for (int tc = 0; tc < 4; ++tc) atomicAdd(ap + tc * 16, run[tc]);
    }
}

// ---------------------------------------------------------------------------
// K3: out = agg / denom + skip (skip already resident in out). Unchanged.
// ---------------------------------------------------------------------------
__global__ __launch_bounds__(256) void finalize(
    const float* __restrict__ agg, const float* __restrict__ denom,
    float* __restrict__ out)
{
    size_t base = ((size_t)blockIdx.x * 256 + threadIdx.x) * 4;
    if (base >= (size_t)N_NODES * 128) return;
    int n = (int)(base >> 7);
    int h = (int)((base >> 6) & 1);
    float dn = denom[(size_t)n * 2 + h];
    float inv = (dn > 0.f) ? (1.f / dn) : 0.f;
    float4 a = *reinterpret_cast<const float4*>(&agg[base]);
    float4 o = *reinterpret_cast<const float4*>(&out[base]);
    o.x += a.x * inv;
    o.y += a.y * inv;
    o.z += a.z * inv;
    o.w += a.w * inv;
    *reinterpret_cast<float4*>(&out[base]) = o;
}

extern "C" void kernel_launch(void* const* d_in, const int* in_sizes, int n_in,
                              void* d_out, int out_size, void* d_ws, size_t ws_size,
                              hipStream_t stream)
{
    const float* x   = (const float*)d_in[0];
    const float* lu  = (const float*)d_in[1];
    const int*   ei  = (const int*)d_in[2];
    const float* t   = (const float*)d_in[3];
    const float* msg = (const float*)d_in[4];
    const float* Wt  = (const float*)d_in[5];
    const float* bt  = (const float*)d_in[6];
    const float* Wq  = (const float*)d_in[7];
    const float* bq  = (const float*)d_in[8];
    const float* Wk  = (const float*)d_in[9];
    const float* bk  = (const float*)d_in[10];
    const float* Wv  = (const float*)d_in[11];
    const float* bv  = (const float*)d_in[12];
    const float* We  = (const float*)d_in[13];
    const float* Wsk = (const float*)d_in[14];
    const float* bsk = (const float*)d_in[15];
    float* out = (float*)d_out;

    float* q    = (float*)d_ws;
    float* k    = q   + (size_t)N_NODES * 128;
    float* v    = k   + (size_t)N_NODES * 128;
    float* agg  = v   + (size_t)N_NODES * 128;
    float* den  = agg + (size_t)N_NODES * 128;
    int*   cnt  = (int*)(den + (size_t)N_NODES * 2);
    int*   cur  = cnt + N_NODES;
    int*   order= cur + N_NODES;
    // cnt (200 KB) dead after scan_kernel, cur after scatter_kernel.
    // Reuse: cnt <- Bhi (64 KB) + WBhi (128 KB); cur <- Blo + WBlo.
    u16* Bhi  = (u16*)cnt;
    u16* Blo  = (u16*)cur;
    u16* WBhi = Bhi + 32768;
    u16* WBlo = Blo + 32768;

    // zero agg + denom + cnt (contiguous)
    hipMemsetAsync(agg, 0,
                   ((size_t)N_NODES * 128 + (size_t)N_NODES * 2 + N_NODES) * sizeof(float),
                   stream);

    hist_kernel<<<dim3((E_EDGES + 255) / 256), 256, 0, stream>>>(ei, cnt);
    scan_kernel<<<dim3(1), 1024, 0, stream>>>(cnt, cur);
    scatter_kernel<<<dim3((E_EDGES + 255) / 256), 256, 0, stream>>>(ei, cur, order);

    pack_weights<<<dim3(48), 256, 0, stream>>>(We, Wq, Wk, Wv, Wsk,
                                               Bhi, Blo, WBhi, WBlo);

    qkvs_mfma<<<dim3(N_NODES / 16), 256, 0, stream>>>(
        x, WBhi, WBlo, bq, bk, bv, bsk, q, k, v, out);

    edge_kernel<<<dim3(E_EDGES / 32), 256, 0, stream>>>(
        order, ei, lu, t, msg, Wt, bt, Bhi, Blo, q, k, v, agg, den);

    finalize<<<dim3((N_NODES * 128 / 4 + 255) / 256), 256, 0, stream>>>(agg, den, out);
}

// Round 4
// 1165.584 us; speedup vs baseline: 1.4507x; 1.0584x over previous
//
#include <hip/hip_runtime.h>
#include <math.h>

#define N_NODES 50000
#define E_EDGES 800000
#define D_DIM 128
#define H_HEADS 2
#define DH_DIM 64
#define C_DIM 256
#define EB 256     // edges per edge_kernel block

typedef unsigned short u16;
typedef unsigned int u32;
typedef __attribute__((ext_vector_type(8))) short short8v;  // 8 bf16 (4 VGPRs)
typedef __attribute__((ext_vector_type(4))) float f32x4;

// bf16 round-to-nearest-even split helpers (Dekker: x = hi + lo exactly to ~2^-17)
static __device__ __forceinline__ u16 f2bf(float x) {
    union { float f; u32 u; } a; a.f = x;
    u32 r = a.u + 0x7fffu + ((a.u >> 16) & 1u);
    return (u16)(r >> 16);
}
static __device__ __forceinline__ float bf2f(u16 h) {
    union { u32 u; float f; } a; a.u = ((u32)h) << 16;
    return a.f;
}

// ---------------------------------------------------------------------------
// pack_weights: We (256x128) and Wq/Wk/Wv/Wskip (128x128) -> bf16 hi/lo MFMA
// B-fragment order. Element j of fragment idx=(KS*8+ct)*64+lane:
//   k = KS*32 + (lane>>4)*8 + j, n = ct*16 + (lane&15).
// We chunk c (K=64) is the contiguous u16 range [c*8192, (c+1)*8192) -> the
// edge kernel stages it into LDS with a straight copy.
// ---------------------------------------------------------------------------
__global__ __launch_bounds__(256) void pack_weights(
    const float* __restrict__ We,
    const float* __restrict__ Wq, const float* __restrict__ Wk,
    const float* __restrict__ Wv, const float* __restrict__ Wsk,
    u16* __restrict__ bhi, u16* __restrict__ blo,
    u16* __restrict__ whi, u16* __restrict__ wlo)
{
    const int idx = blockIdx.x * 256 + threadIdx.x;
    if (idx >= 12288) return;
    const float* W; u16* oh; u16* ol; int kb, n, slot;
    if (idx < 4096) {
        const int lane = idx & 63;
        const int tile = idx >> 6;
        kb = (tile >> 3) * 32 + (lane >> 4) * 8;
        n  = (tile & 7) * 16 + (lane & 15);
        W = We; oh = bhi; ol = blo; slot = idx;
    } else {
        const int idx2 = idx - 4096;
        const int lane = idx2 & 63;
        const int ct = (idx2 >> 6) & 7;
        const int ks = (idx2 >> 9) & 3;
        const int z  = idx2 >> 11;
        W = (z == 0) ? Wq : (z == 1) ? Wk : (z == 2) ? Wv : Wsk;
        kb = ks * 32 + (lane >> 4) * 8;
        n  = ct * 16 + (lane & 15);
        oh = whi; ol = wlo; slot = idx2;
    }
    u32 hw[4], lw[4];
    #pragma unroll
    for (int j = 0; j < 4; ++j) {
        float w0 = W[(size_t)(kb + 2 * j) * 128 + n];
        float w1 = W[(size_t)(kb + 2 * j + 1) * 128 + n];
        u16 h0 = f2bf(w0), h1 = f2bf(w1);
        u16 l0 = f2bf(w0 - bf2f(h0)), l1 = f2bf(w1 - bf2f(h1));
        hw[j] = (u32)h0 | ((u32)h1 << 16);
        lw[j] = (u32)l0 | ((u32)l1 << 16);
    }
    *reinterpret_cast<uint4*>(&oh[(size_t)slot * 8]) = make_uint4(hw[0], hw[1], hw[2], hw[3]);
    *reinterpret_cast<uint4*>(&ol[(size_t)slot * 8]) = make_uint4(lw[0], lw[1], lw[2], lw[3]);
}

// ---------------------------------------------------------------------------
// K1: q/k/v/skip = x @ W + b, split-bf16 MFMA (x-hi * (W-hi + W-lo)).
// Round-4: 64 rows/block, 512 threads, 8 waves = 4 weights x 2 row-halves;
// each wave reuses its register B-fragments across R=2 row-tiles (halves the
// L2 weight re-fetch vs round 3).
// ---------------------------------------------------------------------------
__global__ __launch_bounds__(512, 4) void qkvs_mfma(
    const float* __restrict__ x,
    const u16* __restrict__ WBhi, const u16* __restrict__ WBlo,
    const float* __restrict__ bq, const float* __restrict__ bk,
    const float* __restrict__ bv, const float* __restrict__ bsk,
    float* __restrict__ qo, float* __restrict__ ko, float* __restrict__ vo,
    float* __restrict__ so)
{
    __shared__ __align__(16) u16 sXh[64 * 128];   // 16 KB, swizzled
    const int tid = threadIdx.x;
    const int m0 = blockIdx.x * 64;

    {   // stage x tile as bf16-hi: row = tid>>3, 16-col unit = tid&7
        const int row = tid >> 3;
        const int c16 = (tid & 7) * 16;
        const int gm = m0 + row;
        float vals[16] = {0.f,0.f,0.f,0.f,0.f,0.f,0.f,0.f,
                          0.f,0.f,0.f,0.f,0.f,0.f,0.f,0.f};
        if (gm < N_NODES) {
            #pragma unroll
            for (int i = 0; i < 4; ++i) {
                const float4 a = *reinterpret_cast<const float4*>(
                    &x[(size_t)gm * 128 + c16 + i * 4]);
                vals[i * 4 + 0] = a.x; vals[i * 4 + 1] = a.y;
                vals[i * 4 + 2] = a.z; vals[i * 4 + 3] = a.w;
            }
        }
        char* hB = reinterpret_cast<char*>(sXh);
        const int sw = (row & 15) << 4;
        #pragma unroll
        for (int j4 = 0; j4 < 2; ++j4) {
            u32 hw[4];
            #pragma unroll
            for (int j = 0; j < 4; ++j) {
                const int i = j4 * 8 + j * 2;
                hw[j] = (u32)f2bf(vals[i]) | ((u32)f2bf(vals[i + 1]) << 16);
            }
            const int off = (row * 256 + c16 * 2 + j4 * 16) ^ sw;
            *reinterpret_cast<uint4*>(hB + off) = make_uint4(hw[0], hw[1], hw[2], hw[3]);
        }
    }
    __syncthreads();

    const int lane = tid & 63;
    const int wv = tid >> 6;
    const int z  = wv >> 1;            // weight: 0=q 1=k 2=v 3=skip
    const int rh = wv & 1;             // row-half: tiles {rh*2, rh*2+1}
    const int cl = lane & 15;
    const int g  = lane >> 4;

    f32x4 acc[2][8] = {};
    {
        const char* hB = reinterpret_cast<const char*>(sXh);
        #pragma unroll
        for (int ks = 0; ks < 4; ++ks) {
            short8v a[2];
            #pragma unroll
            for (int tl = 0; tl < 2; ++tl) {
                const int row = (rh * 2 + tl) * 16 + cl;
                const int off = (row * 256 + ks * 64 + g * 16) ^ ((row & 15) << 4);
                a[tl] = *reinterpret_cast<const short8v*>(hB + off);
            }
            #pragma unroll
            for (int ct = 0; ct < 8; ++ct) {
                const int bi = (((z * 4 + ks) * 8 + ct) * 64 + lane) * 8;
                const short8v bh = *reinterpret_cast<const short8v*>(&WBhi[bi]);
                const short8v bl = *reinterpret_cast<const short8v*>(&WBlo[bi]);
                #pragma unroll
                for (int tl = 0; tl < 2; ++tl) {
                    acc[tl][ct] = __builtin_amdgcn_mfma_f32_16x16x32_bf16(a[tl], bh, acc[tl][ct], 0, 0, 0);
                    acc[tl][ct] = __builtin_amdgcn_mfma_f32_16x16x32_bf16(a[tl], bl, acc[tl][ct], 0, 0, 0);
                }
            }
        }
    }

    const float* bias; float* out;
    switch (z) {
        case 0: bias = bq;  out = qo; break;
        case 1: bias = bk;  out = ko; break;
        case 2: bias = bv;  out = vo; break;
        default: bias = bsk; out = so; break;
    }
    #pragma unroll
    for (int tl = 0; tl < 2; ++tl) {
        #pragma unroll
        for (int ct = 0; ct < 8; ++ct) {
            const int col = ct * 16 + cl;
            const float bb = bias[col];
            #pragma unroll
            for (int j = 0; j < 4; ++j) {
                const int gm = m0 + (rh * 2 + tl) * 16 + g * 4 + j;
                if (gm < N_NODES)
                    out[(size_t)gm * 128 + col] = acc[tl][ct][j] + bb;
            }
        }
    }
}

// ---------------------------------------------------------------------------
// CSR build (unchanged): histogram -> scan -> scatter to dst-sorted order.
// ---------------------------------------------------------------------------
__global__ __launch_bounds__(256) void hist_kernel(
    const int* __restrict__ ei, int* __restrict__ cnt)
{
    int e = blockIdx.x * 256 + threadIdx.x;
    if (e < E_EDGES) atomicAdd(&cnt[ei[E_EDGES + e]], 1);
}

__global__ __launch_bounds__(1024) void scan_kernel(
    const int* __restrict__ cnt, int* __restrict__ cur)
{
    __shared__ int part[1024];
    const int t = threadIdx.x;
    const int CH = (N_NODES + 1023) / 1024;
    const int base = t * CH;
    int s = 0;
    for (int i = 0; i < CH; ++i) {
        int idx = base + i;
        if (idx < N_NODES) s += cnt[idx];
    }
    part[t] = s;
    __syncthreads();
    int val = s;
    for (int d = 1; d < 1024; d <<= 1) {
        int other = (t >= d) ? part[t - d] : 0;
        __syncthreads();
        val += other;
        part[t] = val;
        __syncthreads();
    }
    int run = val - s;
    for (int i = 0; i < CH; ++i) {
        int idx = base + i;
        if (idx < N_NODES) {
            cur[idx] = run;
            run += cnt[idx];
        }
    }
}

__global__ __launch_bounds__(256) void scatter_kernel(
    const int* __restrict__ ei, int* __restrict__ cur, int* __restrict__ order)
{
    int e = blockIdx.x * 256 + threadIdx.x;
    if (e < E_EDGES) {
        int p = atomicAdd(&cur[ei[E_EDGES + e]], 1);
        order[p] = e;
    }
}

// ---------------------------------------------------------------------------
// K2: fused edge pipeline, dst-sorted, 256 edges / 512-thr block (8 waves).
// Round-4 restructure (L2-traffic-focused; math identical to round 3):
//  * K-chunked (KC=64) co-staging: attr chunk (bf16-hi, swizzled, 32 KB) and
//    We-fragment chunk (straight copy, 16+16 KB) both in LDS
//  * We L2 traffic: 128 KB per 256-edge block = 0.5 KB/edge (was 8 KB/edge
//    when every wave streamed its B-fragments from L2: 6.4 GB -> 0.4 GB)
//  * wave = (head, tile-quad): 4 row-tiles reuse each B-fragment (R=4)
//  * LDS ~70 KB -> 2 blocks/CU; __launch_bounds__(512,4) caps VGPR at 128
// ---------------------------------------------------------------------------
__global__ __launch_bounds__(512, 4) void edge_kernel(
    const int* __restrict__ order,
    const int* __restrict__ ei,
    const float* __restrict__ last_update,
    const float* __restrict__ t,
    const float* __restrict__ msg,
    const float* __restrict__ Wt,
    const float* __restrict__ bt,
    const u16* __restrict__ Bhi,
    const u16* __restrict__ Blo,
    const float* __restrict__ q,
    const float* __restrict__ k,
    const float* __restrict__ v,
    float* __restrict__ agg,
    float* __restrict__ denom)
{
    __shared__ __align__(16) u16 sA[EB * 64];            // 32 KB attr chunk
    __shared__ __align__(16) u16 sBh[8192], sBl[8192];   // 16+16 KB We chunk
    __shared__ int sSrc[EB], sDst[EB], sEo[EB];
    __shared__ float sRelT[EB];
    __shared__ __align__(16) float sWt[128], sBt[128];

    const int tid = threadIdx.x;
    const int e0 = blockIdx.x * EB;    // 3125*256 == 800000 exactly

    if (tid < EB) {
        int e = order[e0 + tid];
        int s = ei[e];
        sEo[tid] = e;
        sSrc[tid] = s;
        sDst[tid] = ei[E_EDGES + e];
        sRelT[tid] = last_update[s] - t[e];
    } else if (tid < EB + 32) {
        const int i = (tid - EB) * 4;
        *reinterpret_cast<float4*>(&sWt[i]) = *reinterpret_cast<const float4*>(&Wt[i]);
    } else if (tid < EB + 64) {
        const int i = (tid - EB - 32) * 4;
        *reinterpret_cast<float4*>(&sBt[i]) = *reinterpret_cast<const float4*>(&bt[i]);
    }
    __syncthreads();

    const int lane = tid & 63;
    const int wv = tid >> 6;           // 0..7
    const int hh = wv & 1;             // head
    const int wq = wv >> 1;            // tile-quad: tiles wq*4 .. +3
    const int cl = lane & 15;
    const int g  = lane >> 4;

    const int srow  = tid >> 1;        // staging row 0..255
    const int shalf = tid & 1;         // 32-col half
    const float rt = sRelT[srow];
    const int eo = sEo[srow];

    f32x4 acc[4][4] = {};              // [tile][tc]

    #pragma unroll
    for (int c = 0; c < 4; ++c) {
        // ---- stage We chunk: contiguous 8192-u16 copy per array
        {
            const uint4* gh = reinterpret_cast<const uint4*>(&Bhi[c * 8192]);
            const uint4* gl = reinterpret_cast<const uint4*>(&Blo[c * 8192]);
            uint4* sh = reinterpret_cast<uint4*>(sBh);
            uint4* sl = reinterpret_cast<uint4*>(sBl);
            sh[tid]       = gh[tid];
            sh[tid + 512] = gh[tid + 512];
            sl[tid]       = gl[tid];
            sl[tid + 512] = gl[tid + 512];
        }
        // ---- stage attr chunk (cos for c<2, msg for c>=2), bf16-hi, swizzled
        {
            float vals[32];
            if (c < 2) {
                const int cg0 = c * 64 + shalf * 32;
                #pragma unroll
                for (int i = 0; i < 32; ++i)
                    vals[i] = __cosf(fmaf(rt, sWt[cg0 + i], sBt[cg0 + i]));
            } else {
                const int mc = (c - 2) * 64 + shalf * 32;
                #pragma unroll
                for (int i = 0; i < 8; ++i) {
                    const float4 m = *reinterpret_cast<const float4*>(
                        &msg[(size_t)eo * 128 + mc + i * 4]);
                    vals[i * 4 + 0] = m.x; vals[i * 4 + 1] = m.y;
                    vals[i * 4 + 2] = m.z; vals[i * 4 + 3] = m.w;
                }
            }
            char* aB = reinterpret_cast<char*>(sA);
            const int sw = (srow & 7) << 4;
            #pragma unroll
            for (int j4 = 0; j4 < 4; ++j4) {
                u32 hw[4];
                #pragma unroll
                for (int j = 0; j < 4; ++j) {
                    const int i = j4 * 8 + j * 2;
                    hw[j] = (u32)f2bf(vals[i]) | ((u32)f2bf(vals[i + 1]) << 16);
                }
                const int off = (srow * 128 + shalf * 64 + j4 * 16) ^ sw;
                *reinterpret_cast<uint4*>(aB + off) = make_uint4(hw[0], hw[1], hw[2], hw[3]);
            }
        }
        __syncthreads();

        // ---- MFMA: 2 k-steps x 4 col-tiles x 4 row-tiles x (bh + bl)
        {
            const char* aB = reinterpret_cast<const char*>(sA);
            #pragma unroll
            for (int ksl = 0; ksl < 2; ++ksl) {
                short8v a[4];
                #pragma unroll
                for (int tl = 0; tl < 4; ++tl) {
                    const int row = (wq * 4 + tl) * 16 + cl;
                    const int off = (row * 128 + ksl * 64 + g * 16) ^ ((row & 7) << 4);
                    a[tl] = *reinterpret_cast<const short8v*>(aB + off);
                }
                #pragma unroll
                for (int tc = 0; tc < 4; ++tc) {
                    const int bi = ((ksl * 8 + hh * 4 + tc) * 64 + lane) * 8;
                    const short8v bh = *reinterpret_cast<const short8v*>(&sBh[bi]);
                    const short8v bl = *reinterpret_cast<const short8v*>(&sBl[bi]);
                    #pragma unroll
                    for (int tl = 0; tl < 4; ++tl) {
                        acc[tl][tc] = __builtin_amdgcn_mfma_f32_16x16x32_bf16(a[tl], bh, acc[tl][tc], 0, 0, 0);
                        acc[tl][tc] = __builtin_amdgcn_mfma_f32_16x16x32_bf16(a[tl], bl, acc[tl][tc], 0, 0, 0);
                    }
                }
            }
        }
        __syncthreads();
    }

    // ---- epilogue per row-tile: attention, softmax-denom, run-merged atomics
    #pragma unroll
    for (int tl = 0; tl < 4; ++tl) {
        const int ebase = (wq * 4 + tl) * 16 + g * 4;
        int srcs[4], dsts[4];
        #pragma unroll
        for (int r = 0; r < 4; ++r) {
            srcs[r] = sSrc[ebase + r];
            dsts[r] = sDst[ebase + r];
        }
        float ex[4];
        #pragma unroll
        for (int r = 0; r < 4; ++r) {
            float p = 0.f;
            #pragma unroll
            for (int tc = 0; tc < 4; ++tc) {
                const int d = hh * 64 + tc * 16 + cl;
                p = fmaf(q[(size_t)dsts[r] * 128 + d],
                         k[(size_t)srcs[r] * 128 + d] + acc[tl][tc][r], p);
            }
            p += __shfl_xor(p, 1);
            p += __shfl_xor(p, 2);
            p += __shfl_xor(p, 4);
            p += __shfl_xor(p, 8);
            ex[r] = __expf(p * 0.125f);            // 1/sqrt(64)
        }

        if (cl == 0) {
            float dsum = ex[0];
            #pragma unroll
            for (int r = 1; r < 4; ++r) {
                if (dsts[r] == dsts[r - 1]) {
                    dsum += ex[r];
                } else {
                    atomicAdd(&denom[(size_t)dsts[r - 1] * 2 + hh], dsum);
                    dsum = ex[r];
                }
            }
            atomicAdd(&denom[(size_t)dsts[3] * 2 + hh], dsum);
        }

        float run[4];
        int prevDst = dsts[0];
        #pragma unroll
        for (int r = 0; r < 4; ++r) {
            float cur[4];
            #pragma unroll
            for (int tc = 0; tc < 4; ++tc) {
                const int d = hh * 64 + tc * 16 + cl;
                cur[tc] = ex[r] * (v[(size_t)srcs[r] * 128 + d] + acc[tl][tc][r]);
            }
            if (r == 0) {
                #pragma unroll
                for (int tc = 0; tc < 4; ++tc) run[tc] = cur[tc];
            } else if (dsts[r] == prevDst) {
                #pragma unroll
                for (int tc = 0; tc < 4; ++tc) run[tc] += cur[tc];
            } else {
                float* ap = &agg[(size_t)prevDst * 128 + hh * 64 + cl];
                #pragma unroll
                for (int tc = 0; tc < 4; ++tc) atomicAdd(ap + tc * 16, run[tc]);
                #pragma unroll
                for (int tc = 0; tc < 4; ++tc) run[tc] = cur[tc];
                prevDst = dsts[r];
            }
        }
        {
            float* ap = &agg[(size_t)prevDst * 128 + hh * 64 + cl];
            #pragma unroll
            for (int tc = 0; tc < 4; ++tc) atomicAdd(ap + tc * 16, run[tc]);
        }
    }
}

// ---------------------------------------------------------------------------
// K3: out = agg / denom + skip (skip already resident in out). Unchanged.
// ---------------------------------------------------------------------------
__global__ __launch_bounds__(256) void finalize(
    const float* __restrict__ agg, const float* __restrict__ denom,
    float* __restrict__ out)
{
    size_t base = ((size_t)blockIdx.x * 256 + threadIdx.x) * 4;
    if (base >= (size_t)N_NODES * 128) return;
    int n = (int)(base >> 7);
    int h = (int)((base >> 6) & 1);
    float dn = denom[(size_t)n * 2 + h];
    float inv = (dn > 0.f) ? (1.f / dn) : 0.f;
    float4 a = *reinterpret_cast<const float4*>(&agg[base]);
    float4 o = *reinterpret_cast<const float4*>(&out[base]);
    o.x += a.x * inv;
    o.y += a.y * inv;
    o.z += a.z * inv;
    o.w += a.w * inv;
    *reinterpret_cast<float4*>(&out[base]) = o;
}

extern "C" void kernel_launch(void* const* d_in, const int* in_sizes, int n_in,
                              void* d_out, int out_size, void* d_ws, size_t ws_size,
                              hipStream_t stream)
{
    const float* x   = (const float*)d_in[0];
    const float* lu  = (const float*)d_in[1];
    const int*   ei  = (const int*)d_in[2];
    const float* t   = (const float*)d_in[3];
    const float* msg = (const float*)d_in[4];
    const float* Wt  = (const float*)d_in[5];
    const float* bt  = (const float*)d_in[6];
    const float* Wq  = (const float*)d_in[7];
    const float* bq  = (const float*)d_in[8];
    const float* Wk  = (const float*)d_in[9];
    const float* bk  = (const float*)d_in[10];
    const float* Wv  = (const float*)d_in[11];
    const float* bv  = (const float*)d_in[12];
    const float* We  = (const float*)d_in[13];
    const float* Wsk = (const float*)d_in[14];
    const float* bsk = (const float*)d_in[15];
    float* out = (float*)d_out;

    float* q    = (float*)d_ws;
    float* k    = q   + (size_t)N_NODES * 128;
    float* v    = k   + (size_t)N_NODES * 128;
    float* agg  = v   + (size_t)N_NODES * 128;
    float* den  = agg + (size_t)N_NODES * 128;
    int*   cnt  = (int*)(den + (size_t)N_NODES * 2);
    int*   cur  = cnt + N_NODES;
    int*   order= cur + N_NODES;
    // cnt (200 KB) dead after scan_kernel, cur after scatter_kernel.
    // Reuse: cnt <- Bhi (64 KB) + WBhi (128 KB); cur <- Blo + WBlo.
    u16* Bhi  = (u16*)cnt;
    u16* Blo  = (u16*)cur;
    u16* WBhi = Bhi + 32768;
    u16* WBlo = Blo + 32768;

    // zero agg + denom + cnt (contiguous)
    hipMemsetAsync(agg, 0,
                   ((size_t)N_NODES * 128 + (size_t)N_NODES * 2 + N_NODES) * sizeof(float),
                   stream);

    hist_kernel<<<dim3((E_EDGES + 255) / 256), 256, 0, stream>>>(ei, cnt);
    scan_kernel<<<dim3(1), 1024, 0, stream>>>(cnt, cur);
    scatter_kernel<<<dim3((E_EDGES + 255) / 256), 256, 0, stream>>>(ei, cur, order);

    pack_weights<<<dim3(48), 256, 0, stream>>>(We, Wq, Wk, Wv, Wsk,
                                               Bhi, Blo, WBhi, WBlo);

    qkvs_mfma<<<dim3((N_NODES + 63) / 64), 512, 0, stream>>>(
        x, WBhi, WBlo, bq, bk, bv, bsk, q, k, v, out);

    edge_kernel<<<dim3(E_EDGES / EB), 512, 0, stream>>>(
        order, ei, lu, t, msg, Wt, bt, Bhi, Blo, q, k, v, agg, den);

    finalize<<<dim3((N_NODES * 128 / 4 + 255) / 256), 256, 0, stream>>>(agg, den, out);
}